// Round 6
// baseline (783.005 us; speedup 1.0000x reference)
//
#include <hip/hip_runtime.h>
#include <cstdint>
#include <cstddef>

#define TT 64
#define BB 256
#define FEAT 924
#define HH 512
#define NC 151
#define ED 100
#define KIN 1024      // FEAT + ED
#define SIXH 3072
#define FIVEH 2560
#define MROWS (TT * BB)   // 16384
#define RLDS 81920        // Wl: 5 gates x 16 kk x 64 lanes x 16B

typedef __bf16 bf16_t;
typedef __bf16 bf16x8 __attribute__((ext_vector_type(8)));
typedef float f32x4 __attribute__((ext_vector_type(4)));

typedef __attribute__((address_space(1))) const unsigned int* gptr_t;
typedef __attribute__((address_space(3))) unsigned int* lptr_t;

__device__ __forceinline__ void gload16(const void* g, void* l) {
  __builtin_amdgcn_global_load_lds((gptr_t)g, (lptr_t)l, 16, 0, 0);
}

__device__ __forceinline__ f32x4 mfma16(bf16x8 a, bf16x8 b, f32x4 c) {
  return __builtin_amdgcn_mfma_f32_16x16x32_bf16(a, b, c, 0, 0, 0);
}

__device__ __forceinline__ float fsig(float x) {
  return 1.f / (1.f + __expf(-x));
}
__device__ __forceinline__ float ftanh_(float x) {
  return 1.f - 2.f / (1.f + __expf(2.f * x));
}

// ---------------- conversions ----------------
__global__ void k_f2b(const float* __restrict__ in, bf16_t* __restrict__ out, int n) {
  int i = blockIdx.x * 256 + threadIdx.x;
  int stride = gridDim.x * 256;
  for (; i < n; i += stride) out[i] = (bf16_t)in[i];
}

// Wo (151,512) -> zero-padded (256,512) bf16
__global__ void k_wopad(const float* __restrict__ wo, bf16_t* __restrict__ out) {
  int i = blockIdx.x * 256 + threadIdx.x;   // 256*512 = 131072 total
  int r = i >> 9, k = i & 511;
  out[i] = (r < NC) ? (bf16_t)wo[r * HH + k] : (bf16_t)0.f;
}

// TI[row][0..923] = x[row], TI[row][924..1023] = embed[labels[row]]
__global__ void k_gather(const float* __restrict__ x, const int* __restrict__ lab,
                         const float* __restrict__ emb, bf16_t* __restrict__ ti) {
  int row = blockIdx.x;
  int t = threadIdx.x;
  int lb = lab[row];
  const float* xr = x + (size_t)row * FEAT;
  bf16_t* tr = ti + (size_t)row * KIN;
#pragma unroll
  for (int e = 0; e < 4; ++e) {
    int col = t + e * 256;
    float v = (col < FEAT) ? xr[col] : emb[lb * ED + (col - FEAT)];
    tr[col] = (bf16_t)v;
  }
}

// ---------------- generic C = A(M,K) * Bm(N,K)^T + bias, bf16 MFMA ----------------
// 128x128 tile, BK=64, 4 waves; XOR-swizzled LDS (swizzle on global src AND ds_read).
template <typename CT>
__global__ __launch_bounds__(256)
void k_gemm(const bf16_t* __restrict__ A, const bf16_t* __restrict__ Bm,
            const float* __restrict__ bias, CT* __restrict__ C,
            int M, int N, int K, int ldc, int nstore) {
  __shared__ __align__(16) bf16_t As[128 * 64];
  __shared__ __align__(16) bf16_t Bs[128 * 64];
  const int tid = threadIdx.x;
  const int l = tid & 63;
  const int w = tid >> 6;
  const int wr = w >> 1, wc = w & 1;
  const int m0 = blockIdx.y * 128, n0 = blockIdx.x * 128;
  const int l15 = l & 15, lq = l >> 4;

  f32x4 acc[4][4] = {};

  for (int k0 = 0; k0 < K; k0 += 64) {
#pragma unroll
    for (int q = 0; q < 4; ++q) {
      int rig = q * 32 + w * 8 + (l >> 3);
      int kc = (l & 7) ^ (rig & 7);   // source pre-swizzle (both-sides rule #21)
      gload16(A + (size_t)(m0 + rig) * K + k0 + kc * 8, As + q * 2048 + w * 512);
      gload16(Bm + (size_t)(n0 + rig) * K + k0 + kc * 8, Bs + q * 2048 + w * 512);
    }
    __syncthreads();
#pragma unroll
    for (int ks = 0; ks < 2; ++ks) {
      bf16x8 af[4], bf[4];
#pragma unroll
      for (int m = 0; m < 4; ++m) {
        int row = wr * 64 + m * 16 + l15;
        int kcs = (ks * 4 + lq) ^ (row & 7);
        af[m] = *(const bf16x8*)(As + row * 64 + kcs * 8);
      }
#pragma unroll
      for (int n = 0; n < 4; ++n) {
        int row = wc * 64 + n * 16 + l15;
        int kcs = (ks * 4 + lq) ^ (row & 7);
        bf[n] = *(const bf16x8*)(Bs + row * 64 + kcs * 8);
      }
#pragma unroll
      for (int m = 0; m < 4; ++m)
#pragma unroll
        for (int n = 0; n < 4; ++n)
          acc[m][n] = mfma16(af[m], bf[n], acc[m][n]);
    }
    __syncthreads();
  }

#pragma unroll
  for (int n = 0; n < 4; ++n) {
    int ccol = n0 + wc * 64 + n * 16 + l15;
    if (ccol >= nstore) continue;
    float bv = bias[ccol];
#pragma unroll
    for (int m = 0; m < 4; ++m) {
      int crow = m0 + wr * 64 + m * 16 + lq * 4;
#pragma unroll
      for (int j = 0; j < 4; ++j)
        C[(size_t)(crow + j) * ldc + ccol] = (CT)(acc[m][n][j] + bv);
    }
  }
}

// ---------------- persistent recurrence: all 64 steps in one launch ----------------
// grid (8, 32) x 128 thr (2 independent waves after staging). Wave owns 16 b-rows x
// 16 j-cols. Ws slice in LDS (fragment-major, conflict-free); c/mask/pi in registers
// (pi double-buffered prefetch). h exchange via 2-slot fragment-major ring (coalesced
// agent loads/stores); sync via per-wave flags (no atomic RMW, no fences: stores are
// vmcnt-ack'd at the coherence point before the flag store issues).
template <typename PIT>
__global__ __launch_bounds__(128)
void k_recur(const bf16_t* __restrict__ Wsb, const float* __restrict__ bs,
             const PIT* __restrict__ pi, const float* __restrict__ mask,
             bf16_t* __restrict__ Hs, bf16_t* __restrict__ Hf2,
             unsigned* __restrict__ ctr) {
  extern __shared__ __align__(16) char smem[];
  bf16_t* Wl = (bf16_t*)smem;              // [5][16][64 lanes][8] fragment-major
  const int tid = threadIdx.x;
  const int l = tid & 63;
  const int w = tid >> 6;                  // wave: b-half
  const int l15 = l & 15, lq = l >> 4;
  const int bq = blockIdx.x, jq = blockIdx.y;
  const int b0 = bq * 32, j0 = jq * 16;
  const int j = j0 + l15;
  const int brow = b0 + w * 16;            // this wave's 16-row block base
  unsigned* flags = ctr + bq * 64;         // 64 wave-flags per b-group (256B line)

  union U8 { unsigned long long q[2]; bf16x8 v; };
  union CV { bf16_t b; unsigned short u; };

  // pi prefetch registers (static indexing only)
  float pvA[4][6], pvB[4][6];
  auto loadpi = [&](int t, float (*pv)[6]) {
    const PIT* pit = pi + (size_t)t * BB * SIXH;
#pragma unroll
    for (int r = 0; r < 4; ++r) {
      const PIT* prow = pit + (size_t)(brow + lq * 4 + r) * SIXH + j;
#pragma unroll
      for (int g = 0; g < 6; ++g) pv[r][g] = (float)prow[g * HH];
    }
  };

  loadpi(0, pvA);

  // one-time: build fragment-major Wl. slot s = g*16+kk; each wave does 40 slots.
  for (int s = w * 40; s < w * 40 + 40; ++s) {
    int g = s >> 4, kk = s & 15;
    bf16x8 frag = *(const bf16x8*)(Wsb + (size_t)(g * HH + j0 + l15) * HH + kk * 32 + lq * 8);
    *(bf16x8*)(Wl + (size_t)s * 512 + l * 8) = frag;
  }
  __syncthreads();

  float bsr[5];
#pragma unroll
  for (int g = 0; g < 5; ++g) bsr[g] = bs[g * HH + j];
  float mreg[4], creg[4] = {0.f, 0.f, 0.f, 0.f};
#pragma unroll
  for (int r = 0; r < 4; ++r)
    mreg[r] = mask[(size_t)(brow + lq * 4 + r) * HH + j];

  // frag-major layouts: slot stride BB*HH; bq stride 32*512; kk stride 1024; row stride 32
  const int myflag = jq * 2 + w;

  for (int t = 0; t < TT; ++t) {
    f32x4 acc[5] = {};
    U8 au[16];

    if (t > 0) {
      // wait: all 64 waves of this b-group published h_t (coalesced 256B flag poll)
      unsigned tgt = (unsigned)t;
      while (true) {
        unsigned v = __hip_atomic_load(flags + l, __ATOMIC_RELAXED, __HIP_MEMORY_SCOPE_AGENT);
        if (__all((int)(v >= tgt))) break;
        __builtin_amdgcn_s_sleep(1);
      }

      // A-fragments: coalesced agent loads from frag-major ring slot t&1
      const bf16_t* hb = Hf2 + (size_t)(t & 1) * BB * HH + (size_t)bq * 16384
                       + (size_t)(w * 16 + l15) * 32 + lq * 8;
#pragma unroll
      for (int kk = 0; kk < 16; ++kk) {
        unsigned long long* p = (unsigned long long*)(hb + kk * 1024);
        au[kk].q[0] = __hip_atomic_load(p, __ATOMIC_RELAXED, __HIP_MEMORY_SCOPE_AGENT);
        au[kk].q[1] = __hip_atomic_load(p + 1, __ATOMIC_RELAXED, __HIP_MEMORY_SCOPE_AGENT);
      }
    }

    // prefetch next step's pi (latency hides under MFMA + publish + next poll)
    if (t + 1 < TT) loadpi(t + 1, pvB);

    if (t > 0) {
#pragma unroll
      for (int kk = 0; kk < 16; ++kk) {
        bf16x8 a = au[kk].v;
#pragma unroll
        for (int g = 0; g < 5; ++g) {
          bf16x8 bb = *(const bf16x8*)(Wl + (size_t)(g * 16 + kk) * 512 + l * 8);
          acc[g] = mfma16(a, bb, acc[g]);
        }
      }
    }

    // fused gates / state / highway / dropout; dual-publish h_{t+1}
    bf16_t* hsN = Hs + (size_t)(t + 1) * BB * HH;                    // row-major (final GEMM)
    bf16_t* hfN = Hf2 + (size_t)((t + 1) & 1) * BB * HH + (size_t)bq * 16384
                + (size_t)(jq >> 1) * 1024 + (jq & 1) * 16 + l15;    // frag-major ring
#pragma unroll
    for (int r = 0; r < 4; ++r) {
      int row = w * 16 + lq * 4 + r;
      int b = b0 + row;
      float ig = fsig(pvA[r][0] + acc[0][r] + bsr[0]);
      float fg = fsig(pvA[r][1] + acc[1][r] + bsr[1]);
      float mi = ftanh_(pvA[r][2] + acc[2][r] + bsr[2]);
      float og = fsig(pvA[r][3] + acc[3][r] + bsr[3]);
      float hg = fsig(pvA[r][4] + acc[4][r] + bsr[4]);
      float cn = ig * mi + fg * creg[r];
      creg[r] = cn;
      float o = og * ftanh_(cn);
      o = hg * o + (1.f - hg) * pvA[r][5];
      o *= mreg[r];
      CV cv; cv.b = (bf16_t)o;
      hsN[(size_t)b * HH + j] = cv.b;
      __hip_atomic_store((unsigned short*)(hfN + (size_t)row * 32), cv.u,
                         __ATOMIC_RELAXED, __HIP_MEMORY_SCOPE_AGENT);
    }

    // release: ack all stores at coherence point, then publish this wave's flag
    asm volatile("s_waitcnt vmcnt(0)" ::: "memory");
    if (l == 0)
      __hip_atomic_store(flags + myflag, (unsigned)(t + 1),
                         __ATOMIC_RELAXED, __HIP_MEMORY_SCOPE_AGENT);

    // rotate pi buffers (static unrolled copy)
#pragma unroll
    for (int r = 0; r < 4; ++r)
#pragma unroll
      for (int g = 0; g < 6; ++g) pvA[r][g] = pvB[r][g];
  }
}

// ---------------- launcher ----------------
extern "C" void kernel_launch(void* const* d_in, const int* in_sizes, int n_in,
                              void* d_out, int out_size, void* d_ws, size_t ws_size,
                              hipStream_t stream) {
  const float* x    = (const float*)d_in[0];
  const int*   lab  = (const int*)d_in[1];
  const float* emb  = (const float*)d_in[2];
  const float* Wi   = (const float*)d_in[3];
  const float* bi   = (const float*)d_in[4];
  const float* Ws   = (const float*)d_in[5];
  const float* bs   = (const float*)d_in[6];
  const float* Wo   = (const float*)d_in[7];
  const float* bo   = (const float*)d_in[8];
  const float* mask = (const float*)d_in[9];
  float* out = (float*)d_out;

  char* w = (char*)d_ws;
  size_t off = 0;
  auto take = [&](size_t bytes) {
    void* p = w + off;
    off += (bytes + 255) & ~(size_t)255;
    return p;
  };

  bf16_t*   TI   = (bf16_t*)take((size_t)MROWS * KIN * 2);
  bf16_t*   Wib  = (bf16_t*)take((size_t)SIXH * KIN * 2);
  bf16_t*   Wsb  = (bf16_t*)take((size_t)FIVEH * HH * 2);
  bf16_t*   Wob  = (bf16_t*)take((size_t)256 * HH * 2);
  bf16_t*   Hs   = (bf16_t*)take((size_t)(TT + 1) * BB * HH * 2);
  bf16_t*   Hf2  = (bf16_t*)take((size_t)2 * BB * HH * 2);   // frag-major h ring
  unsigned* ctrs = (unsigned*)take(8 * 64 * sizeof(unsigned));
  void* piPtr = w + off;
  size_t avail = (ws_size > off) ? (ws_size - off) : 0;

  bool pifp32 = avail >= (size_t)MROWS * SIXH * 4;
  bool pibf16 = !pifp32 && avail >= (size_t)MROWS * SIXH * 2;
  if (!pifp32 && !pibf16) {
    hipMemsetAsync(d_out, 0, (size_t)out_size * 4, stream);  // diagnostic: ws too small
    return;
  }

  // weight conversions + input gather/concat + flag init
  k_f2b<<<dim3(1024), dim3(256), 0, stream>>>(Wi, Wib, SIXH * KIN);
  k_f2b<<<dim3(512), dim3(256), 0, stream>>>(Ws, Wsb, FIVEH * HH);
  k_wopad<<<dim3(512), dim3(256), 0, stream>>>(Wo, Wob);
  k_gather<<<dim3(MROWS), dim3(256), 0, stream>>>(x, lab, emb, TI);
  hipMemsetAsync(ctrs, 0, 8 * 64 * sizeof(unsigned), stream);

  dim3 rg(8, 32), rb(128);
  if (pifp32) {
    float* pi = (float*)piPtr;
    k_gemm<float><<<dim3(SIXH / 128, MROWS / 128), dim3(256), 0, stream>>>(
        TI, Wib, bi, pi, MROWS, SIXH, KIN, SIXH, SIXH);
    const float* piC = pi;
    hipFuncSetAttribute((const void*)k_recur<float>,
                        hipFuncAttributeMaxDynamicSharedMemorySize, RLDS);
    void* args[7] = {&Wsb, &bs, &piC, &mask, &Hs, &Hf2, &ctrs};
    hipError_t e = hipLaunchCooperativeKernel((void*)k_recur<float>, rg, rb, args,
                                              RLDS, stream);
    if (e != hipSuccess)
      k_recur<float><<<rg, rb, RLDS, stream>>>(Wsb, bs, piC, mask, Hs, Hf2, ctrs);
  } else {
    bf16_t* pi = (bf16_t*)piPtr;
    k_gemm<bf16_t><<<dim3(SIXH / 128, MROWS / 128), dim3(256), 0, stream>>>(
        TI, Wib, bi, pi, MROWS, SIXH, KIN, SIXH, SIXH);
    const bf16_t* piC = pi;
    hipFuncSetAttribute((const void*)k_recur<bf16_t>,
                        hipFuncAttributeMaxDynamicSharedMemorySize, RLDS);
    void* args[7] = {&Wsb, &bs, &piC, &mask, &Hs, &Hf2, &ctrs};
    hipError_t e = hipLaunchCooperativeKernel((void*)k_recur<bf16_t>, rg, rb, args,
                                              RLDS, stream);
    if (e != hipSuccess)
      k_recur<bf16_t><<<rg, rb, RLDS, stream>>>(Wsb, bs, piC, mask, Hs, Hf2, ctrs);
  }

  // batched output projection: pred = h @ Wo^T + bo  (Wo zero-padded to 256 rows)
  k_gemm<float><<<dim3(2, MROWS / 128), dim3(256), 0, stream>>>(
      Hs + (size_t)BB * HH, Wob, bo, out, MROWS, 256, HH, NC, NC);
}